// Round 11
// baseline (399.359 us; speedup 1.0000x reference)
//
#include <hip/hip_runtime.h>
#include <hip/hip_bf16.h>
#include <hip/hip_cooperative_groups.h>

namespace cg = cooperative_groups;

#define N_NODES 50000
#define N_EDGES 800000
#define IN_DIM  256
#define OUT_DIM 128

#define NBINS    512          // bins of 98 rows: 512*98 = 50176 >= 50000
#define RPB      98
#define BIN_CAP  1900         // mean 1568 + 8.4 sigma (sigma ~ 39.6)
#define EPB      2048         // edges per bin job (1024 thr x 2)
#define NBJOBS   391          // ceil(800000/2048)
#define NGJOBS   782          // gemm stages of 64 rows
#define NJOBS    (NBJOBS + NGJOBS)
#define APITCH   264          // LDS A-pitch bf16: 132 dw -> m*4 banks, 2-way max (free)

typedef __bf16 bf16x8 __attribute__((ext_vector_type(8)));
typedef float  f32x4  __attribute__((ext_vector_type(4)));

// bin = floor(r/98) via 64-bit magic: (r*171197)>>24, exact for r < 50176
// (proof: 98*171197 = 2^24+90; err 90k+16606109 < 2^24 for k<1901)
__device__ __forceinline__ unsigned bin_of(unsigned r) {
    return (unsigned)(((unsigned long long)r * 171197ull) >> 24);
}
__device__ __forceinline__ float blo(unsigned u) { return __uint_as_float(u << 16); }
__device__ __forceinline__ float bhi(unsigned u) { return __uint_as_float(u & 0xffff0000u); }

// ---------------------------------------------------------------------------
// ws layout (bytes)
// ---------------------------------------------------------------------------
#define WT_OFF   0                      // 64 KB    : Wt bf16 [128][256]
#define SUP_OFF  65536                  // 12.8 MB  : support u32 [50000][64] planar-pair
#define BIN_OFF  12865536               // 7.78 MB  : binbuf int2[512*1900]
#define CUR_OFF  20647936               // 2 KB     : bin_cursor int[512]

// ---------------------------------------------------------------------------
// Shared-memory union (33,792 B max -> 1 block/CU guaranteed)
// ---------------------------------------------------------------------------
struct ShBin {                         // 26,624 B
    int2 stage[EPB];
    int  cnt[NBINS], off[NBINS], base[NBINS], cur[NBINS], s[NBINS];
};
struct ShSrt {                         // 32,448 B
    int2 stage[BIN_CAP];
    int2 sorted_[BIN_CAP];
    int  cnt[128], off[128], cur[128], s[128];
};
union Sh {
    __bf16 a[64 * APITCH];             // 33,792 B (gemm A-tile)
    ShBin  bin;
    ShSrt  srt;
};

// ---------------------------------------------------------------------------
// Phase bodies (shared between cooperative kernel and fallback kernels)
// ---------------------------------------------------------------------------
__device__ __forceinline__ void do_prep(int g, const float* __restrict__ W,
                                        __bf16* __restrict__ Wt,
                                        int* __restrict__ bin_cursor) {
    if (g < 32768) { int n = g >> 8, k = g & 255; Wt[g] = (__bf16)W[k * OUT_DIM + n]; }
    if (g < NBINS) bin_cursor[g] = g * BIN_CAP;
}

__device__ __forceinline__ void do_bin_job(Sh& sh, int t, int jb,
                                           const int* __restrict__ rows,
                                           const int* __restrict__ cols,
                                           const float* __restrict__ vals,
                                           int* __restrict__ bin_cursor,
                                           int2* __restrict__ binbuf) {
    long e0 = (long)jb * EPB;
    if (t < NBINS) sh.bin.cnt[t] = 0;
    __syncthreads();
#pragma unroll
    for (int k = 0; k < 2; ++k) {
        long e = e0 + k * 1024 + t;
        if (e < N_EDGES) atomicAdd(&sh.bin.cnt[bin_of((unsigned)rows[e])], 1);
    }
    __syncthreads();
    int v = 0;
    if (t < NBINS) { v = sh.bin.cnt[t]; sh.bin.s[t] = v; }
    __syncthreads();
#pragma unroll
    for (int o = 1; o < NBINS; o <<= 1) {
        int xv = 0;
        if (t < NBINS && t >= o) xv = sh.bin.s[t - o];
        __syncthreads();
        if (t < NBINS) sh.bin.s[t] += xv;
        __syncthreads();
    }
    if (t < NBINS) {
        sh.bin.off[t]  = sh.bin.s[t] - v;
        sh.bin.cur[t]  = sh.bin.s[t] - v;
        sh.bin.base[t] = atomicAdd(&bin_cursor[t], v);   // 1 global atomic/bin
    }
    __syncthreads();
#pragma unroll
    for (int k = 0; k < 2; ++k) {
        long e = e0 + k * 1024 + t;
        if (e < N_EDGES) {
            unsigned r = (unsigned)rows[e];
            unsigned c = (unsigned)cols[e];
            float    w = vals[e];
            int pos = atomicAdd(&sh.bin.cur[bin_of(r)], 1);
            sh.bin.stage[pos] = make_int2((int)((r << 16) | c), __float_as_int(w));
        }
    }
    __syncthreads();
    long rem = N_EDGES - e0;
    int nblk = rem < EPB ? (int)rem : EPB;
    for (int i = t; i < nblk; i += 1024) {
        int2 rec = sh.bin.stage[i];
        unsigned bn = bin_of(((unsigned)rec.x) >> 16);
        int dst = sh.bin.base[bn] + (i - sh.bin.off[bn]);
        if (dst < (int)(bn + 1) * BIN_CAP)               // statistical guard
            binbuf[dst] = rec;
    }
}

__device__ __forceinline__ void do_gemm_job(Sh& sh, int t, int gs,
                                            const float* __restrict__ x,
                                            const __bf16* __restrict__ Wt,
                                            unsigned* __restrict__ sup32) {
    long r0 = (long)gs * 64;
    const float4* xv = (const float4*)(x + r0 * IN_DIM);
#pragma unroll
    for (int it = 0; it < 4; ++it) {
        int idx = it * 1024 + t;                   // float4 index, [0,4096)
        int row = idx >> 6;                        // 64 float4 per row
        int col = idx & 63;
        if (r0 + row < N_NODES) {
            float4 f = xv[idx];
            __bf16 c0 = (__bf16)f.x, c1 = (__bf16)f.y;
            __bf16 c2 = (__bf16)f.z, c3 = (__bf16)f.w;
            unsigned lo = (unsigned)*(unsigned short*)&c0 |
                          ((unsigned)*(unsigned short*)&c1 << 16);
            unsigned hi = (unsigned)*(unsigned short*)&c2 |
                          ((unsigned)*(unsigned short*)&c3 << 16);
            *(uint2*)(&sh.a[row * APITCH + col * 4]) = make_uint2(lo, hi);
        }
    }
    __syncthreads();

    int wave = t >> 6, lane = t & 63;
    int tl   = wave >> 2;                          // tile-local 0..3
    int q    = wave & 3;                           // col quarter: nt pair {q, q+4}
    int tile = gs * 4 + tl;
    if (tile < 3125) {
        int m = lane & 15, quad = lane >> 4;
        f32x4 accL = (f32x4){0,0,0,0}, accH = (f32x4){0,0,0,0};
        const __bf16* ap  = sh.a + (tl * 16 + m) * APITCH + quad * 8;
        const __bf16* wpL = Wt + (q)     * 16 * IN_DIM + m * IN_DIM + quad * 8;
        const __bf16* wpH = Wt + (q + 4) * 16 * IN_DIM + m * IN_DIM + quad * 8;
#pragma unroll
        for (int ks = 0; ks < 8; ++ks) {
            bf16x8 af = *(const bf16x8*)(ap  + ks * 32);   // ds_read_b128
            bf16x8 bL = *(const bf16x8*)(wpL + ks * 32);
            bf16x8 bH = *(const bf16x8*)(wpH + ks * 32);
            accL = __builtin_amdgcn_mfma_f32_16x16x32_bf16(af, bL, accL, 0, 0, 0);
            accH = __builtin_amdgcn_mfma_f32_16x16x32_bf16(af, bH, accH, 0, 0, 0);
        }
        // planar-pair epilogue (mapping verified R7-R9): word j=q*16+m packs
        // ch j (accL, nt=q) and ch j+64 (accH, nt=q+4)
        unsigned* op = sup32 + (long)tile * 16 * 64;
#pragma unroll
        for (int r = 0; r < 4; ++r) {
            __bf16 lo = (__bf16)accL[r], hi = (__bf16)accH[r];
            unsigned w = (unsigned)*(unsigned short*)&lo |
                         ((unsigned)*(unsigned short*)&hi << 16);
            op[(quad * 4 + r) * 64 + q * 16 + m] = w;
        }
    }
}

__device__ __forceinline__ void do_srt(Sh& sh, int t, int b,
                                       const int* __restrict__ bin_cursor,
                                       const int2* __restrict__ binbuf,
                                       const unsigned* __restrict__ sup32,
                                       const float* __restrict__ bias,
                                       float* __restrict__ out) {
    int row0 = b * RPB;
    int n = bin_cursor[b] - b * BIN_CAP;
    n = n < 0 ? 0 : (n > BIN_CAP ? BIN_CAP : n);
    const int2* seg = binbuf + (long)b * BIN_CAP;

    if (t < 128) sh.srt.cnt[t] = 0;
    __syncthreads();
    for (int i = t; i < n; i += 1024) {
        int2 rec = seg[i];
        sh.srt.stage[i] = rec;
        atomicAdd(&sh.srt.cnt[(int)(((unsigned)rec.x) >> 16) - row0], 1);
    }
    __syncthreads();
    int v = 0;
    if (t < 128) { v = sh.srt.cnt[t]; sh.srt.s[t] = v; }
    __syncthreads();
#pragma unroll
    for (int o = 1; o < 128; o <<= 1) {
        int xv = 0;
        if (t < 128 && t >= o) xv = sh.srt.s[t - o];
        __syncthreads();
        if (t < 128) sh.srt.s[t] += xv;
        __syncthreads();
    }
    if (t < 128) { sh.srt.off[t] = sh.srt.s[t] - v; sh.srt.cur[t] = 0; }
    __syncthreads();
    for (int i = t; i < n; i += 1024) {
        int2 rec = sh.srt.stage[i];
        int rl = (int)(((unsigned)rec.x) >> 16) - row0;
        sh.srt.sorted_[sh.srt.off[rl] + atomicAdd(&sh.srt.cur[rl], 1)] = rec;
    }
    __syncthreads();

    int wave = t >> 6, lane = t & 63;
    float bb0 = bias[lane], bb1 = bias[64 + lane];
    for (int rl = wave; rl < RPB; rl += 16) {
        int row = row0 + rl;
        if (row < N_NODES) {
            int st = sh.srt.off[rl], nd = sh.srt.cnt[rl];
            float a0 = 0.f, a1 = 0.f;
            int i = 0;
            for (; i + 8 <= nd; i += 8) {
                int2 e[8]; unsigned u[8];
#pragma unroll
                for (int jj = 0; jj < 8; ++jj) e[jj] = sh.srt.sorted_[st + i + jj];
#pragma unroll
                for (int jj = 0; jj < 8; ++jj)
                    u[jj] = sup32[(long)(((unsigned)e[jj].x) & 0xffffu) * 64 + lane];
#pragma unroll
                for (int jj = 0; jj < 8; ++jj) {
                    float vv = __int_as_float(e[jj].y);
                    a0 += vv * blo(u[jj]); a1 += vv * bhi(u[jj]);
                }
            }
            for (; i < nd; ++i) {
                int2 ev = sh.srt.sorted_[st + i];
                unsigned uu = sup32[(long)(((unsigned)ev.x) & 0xffffu) * 64 + lane];
                float vv = __int_as_float(ev.y);
                a0 += vv * blo(uu); a1 += vv * bhi(uu);
            }
            out[(long)row * 128 + lane]      = a0 + bb0;
            out[(long)row * 128 + 64 + lane] = a1 + bb1;
        }
    }
}

// ---------------------------------------------------------------------------
// Cooperative mega-kernel: 256 blocks x 1024 thr (1 block/CU guaranteed).
// ---------------------------------------------------------------------------
__global__ __launch_bounds__(1024, 4) void k_all(const float* __restrict__ x,
                                                 const float* __restrict__ W,
                                                 __bf16* __restrict__ Wt,
                                                 unsigned* __restrict__ sup32,
                                                 const int* __restrict__ rows,
                                                 const int* __restrict__ cols,
                                                 const float* __restrict__ vals,
                                                 int* __restrict__ bin_cursor,
                                                 int2* __restrict__ binbuf,
                                                 const float* __restrict__ bias,
                                                 float* __restrict__ out) {
    __shared__ Sh sh;
    cg::grid_group grid = cg::this_grid();
    int t = threadIdx.x;

    do_prep(blockIdx.x * 1024 + t, W, Wt, bin_cursor);
    __threadfence();
    grid.sync();

    for (int j = blockIdx.x; j < NJOBS; j += gridDim.x) {
        __syncthreads();                           // protect LDS union reuse
        if (j < NBJOBS) do_bin_job(sh, t, j, rows, cols, vals, bin_cursor, binbuf);
        else            do_gemm_job(sh, t, j - NBJOBS, x, Wt, sup32);
    }
    __threadfence();
    grid.sync();

    for (int b = blockIdx.x; b < NBINS; b += gridDim.x) {
        __syncthreads();
        do_srt(sh, t, b, bin_cursor, binbuf, sup32, bias, out);
    }
}

// ---------------------------------------------------------------------------
// Fallback (non-cooperative) kernels — same bodies, 3 launches.
// ---------------------------------------------------------------------------
__global__ __launch_bounds__(1024) void k_p1(const float* __restrict__ W,
                                             __bf16* __restrict__ Wt,
                                             int* __restrict__ bin_cursor) {
    do_prep(blockIdx.x * 1024 + threadIdx.x, W, Wt, bin_cursor);
}

__global__ __launch_bounds__(1024, 4) void k_p2(const float* __restrict__ x,
                                                const __bf16* __restrict__ Wt,
                                                unsigned* __restrict__ sup32,
                                                const int* __restrict__ rows,
                                                const int* __restrict__ cols,
                                                const float* __restrict__ vals,
                                                int* __restrict__ bin_cursor,
                                                int2* __restrict__ binbuf) {
    __shared__ Sh sh;
    int t = threadIdx.x;
    for (int j = blockIdx.x; j < NJOBS; j += gridDim.x) {
        __syncthreads();
        if (j < NBJOBS) do_bin_job(sh, t, j, rows, cols, vals, bin_cursor, binbuf);
        else            do_gemm_job(sh, t, j - NBJOBS, x, Wt, sup32);
    }
}

__global__ __launch_bounds__(1024, 4) void k_p3(const int* __restrict__ bin_cursor,
                                                const int2* __restrict__ binbuf,
                                                const unsigned* __restrict__ sup32,
                                                const float* __restrict__ bias,
                                                float* __restrict__ out) {
    __shared__ Sh sh;
    int t = threadIdx.x;
    for (int b = blockIdx.x; b < NBINS; b += gridDim.x) {
        __syncthreads();
        do_srt(sh, t, b, bin_cursor, binbuf, sup32, bias, out);
    }
}

// ---------------------------------------------------------------------------
extern "C" void kernel_launch(void* const* d_in, const int* in_sizes, int n_in,
                              void* d_out, int out_size, void* d_ws, size_t ws_size,
                              hipStream_t stream) {
    const int*   adj_rows = (const int*)  d_in[0];
    const int*   adj_cols = (const int*)  d_in[1];
    const float* adj_vals = (const float*)d_in[2];
    const float* x        = (const float*)d_in[3];
    const float* W        = (const float*)d_in[4];
    const float* b        = (const float*)d_in[5];
    float* out = (float*)d_out;

    char* ws = (char*)d_ws;
    __bf16*   Wt         = (__bf16*)  (ws + WT_OFF);
    unsigned* sup32      = (unsigned*)(ws + SUP_OFF);
    int2*     binbuf     = (int2*)    (ws + BIN_OFF);
    int*      bin_cursor = (int*)     (ws + CUR_OFF);

    void* args[] = { (void*)&x, (void*)&W, (void*)&Wt, (void*)&sup32,
                     (void*)&adj_rows, (void*)&adj_cols, (void*)&adj_vals,
                     (void*)&bin_cursor, (void*)&binbuf, (void*)&b, (void*)&out };

    hipError_t err = hipLaunchCooperativeKernel((const void*)k_all,
                                                dim3(256), dim3(1024),
                                                args, 0, stream);
    if (err != hipSuccess) {
        // co-residency or capture rejection: same phases, 3 regular launches
        (void)hipGetLastError();                   // clear sticky error
        k_p1<<<32,  1024, 0, stream>>>(W, Wt, bin_cursor);
        k_p2<<<256, 1024, 0, stream>>>(x, Wt, sup32, adj_rows, adj_cols, adj_vals,
                                       bin_cursor, binbuf);
        k_p3<<<256, 1024, 0, stream>>>(bin_cursor, binbuf, sup32, b, out);
    }
}